// Round 5
// baseline (418.692 us; speedup 1.0000x reference)
//
#include <hip/hip_runtime.h>

// ---------------------------------------------------------------------------
// MultiHeadAttentionBlock: B=2, S=2048, D=1024, H=16, DK=64, causal.
// FP32 I/O; bf16 MFMA compute, fp32 accumulate.
// r11: register-lean single-strip attention. Evidence r6/r7/r8: resident
//      waves/CU ~ 850/VGPR (r7 64VGPR->13.4 waves vs r8 128VGPR->6.1, same
//      grid). attn is latency-bound (7700 cyc/iter vs ~2000 instr content).
//      => one 16-row strip per wave, KVBLK=32, K/V frags 16+16 VGPR with
//      disjoint lifetimes, no double-buffer, __launch_bounds__(64,6) (cap 85).
//      4096 waves, longest strips first, bh-major co-residency for L1 reuse.
//      GEMMs/cvt identical to r10.
// ---------------------------------------------------------------------------

typedef __attribute__((ext_vector_type(8))) short bf16x8;     // 8 bf16 = 4 VGPRs
typedef __attribute__((ext_vector_type(4))) float floatx4;    // MFMA C/D
typedef __attribute__((ext_vector_type(4))) unsigned short u16x4;  // 8B packed bf16

#define S_LEN 2048
#define D_MODEL 1024
#define N_HEADS 16
#define D_HEAD 64
#define M_ROWS 4096   // B*S
#define QSCALE 0.18033688011112042f  // 0.125 * log2(e)

#define XSTR 1088   // padded row stride (elems) for [*,1024] bf16 buffers
#define VSTR 4160   // padded row stride (elems) for Vt [1024][4096]

__device__ __forceinline__ unsigned short f32_to_bf16(float f) {
  unsigned int u = __builtin_bit_cast(unsigned int, f);
  u += 0x7FFFu + ((u >> 16) & 1u);  // RNE
  return (unsigned short)(u >> 16);
}

// async 16B global->LDS copy: LDS dest is wave-uniform base + lane*16.
__device__ __forceinline__ void async_lds16(const unsigned short* g, unsigned short* l) {
  __builtin_amdgcn_global_load_lds(
      (const __attribute__((address_space(1))) unsigned int*)g,
      (__attribute__((address_space(3))) unsigned int*)l, 16, 0, 0);
}

// ---------------------------------------------------------------------------
// fp32 -> bf16 pre-passes (row-per-block, writing padded rows).
// ---------------------------------------------------------------------------
__global__ __launch_bounds__(256) void cvt_w(
    const float* __restrict__ w0, const float* __restrict__ w1,
    const float* __restrict__ w2, const float* __restrict__ w3,
    unsigned short* __restrict__ dst) {
  const int row = blockIdx.x;       // 0..1023
  const int z = blockIdx.y;         // 0..3
  const float* src = ((z == 0) ? w0 : (z == 1) ? w1 : (z == 2) ? w2 : w3) + (long)row * 1024;
  unsigned short* d = dst + (long)z * 1024 * XSTR + (long)row * XSTR;
  const int tid = threadIdx.x;
  float4 f = ((const float4*)src)[tid];
  u16x4 o;
  o[0] = f32_to_bf16(f.x); o[1] = f32_to_bf16(f.y);
  o[2] = f32_to_bf16(f.z); o[3] = f32_to_bf16(f.w);
  *(u16x4*)(d + tid * 4) = o;
}

__global__ __launch_bounds__(256) void cvt_x(
    const float* __restrict__ x0, const float* __restrict__ x1,
    const float* __restrict__ x2, unsigned short* __restrict__ dst) {
  const int row = blockIdx.x;       // 0..4095
  const int z = blockIdx.y;         // 0..2
  const float* src = ((z == 0) ? x0 : (z == 1) ? x1 : x2) + (long)row * 1024;
  unsigned short* d = dst + (long)z * M_ROWS * XSTR + (long)row * XSTR;
  const int tid = threadIdx.x;
  float4 f = ((const float4*)src)[tid];
  u16x4 o;
  o[0] = f32_to_bf16(f.x); o[1] = f32_to_bf16(f.y);
  o[2] = f32_to_bf16(f.z); o[3] = f32_to_bf16(f.w);
  *(u16x4*)(d + tid * 4) = o;
}

// ---------------------------------------------------------------------------
// Fused QKV projection. z = blockIdx.z.  Y = X @ W^T + b.
// 128x128 tile, BK=64, 4 waves x (64x64).  global_load_lds staging into
// linear [128][64] LDS, 2 barriers per K-step.  All bf16 operands padded.
// z=0: Y = (X Wq^T + bq) * QSCALE.  z=1: plain.  z=2: Y^T (V transposed).
// ---------------------------------------------------------------------------
#define GK 1024
#define GN 1024

template <bool XPRE>
__global__ __launch_bounds__(256, 3) void qkv_gemm(
    const float* __restrict__ Xq, const float* __restrict__ Xk, const float* __restrict__ Xv,
    const unsigned short* __restrict__ Xb,  // bf16, 3 x [4096][XSTR] (XPRE only)
    const unsigned short* __restrict__ Wb,  // bf16, 4 x [1024][XSTR]: [wq|wk|wv|wo]
    const float* __restrict__ bq, const float* __restrict__ bk, const float* __restrict__ bv,
    unsigned short* __restrict__ Yq, unsigned short* __restrict__ Yk,
    unsigned short* __restrict__ Yvt) {
  __shared__ __align__(16) unsigned short As[128 * 64];  // linear, stride 64
  __shared__ __align__(16) unsigned short Bs[128 * 64];

  const int z = blockIdx.z;
  const unsigned short* W = Wb + (long)z * 1024 * XSTR;
  const float* bias = (z == 0) ? bq : ((z == 1) ? bk : bv);

  const int r0 = blockIdx.x * 128;
  const int n0 = blockIdx.y * 128;
  const int tid = threadIdx.x;
  const int lane = tid & 63;
  const int wave = tid >> 6;
  const int quad = lane >> 4;
  const int ln = lane & 15;
  const int wm = (wave >> 1) * 64;
  const int wn = (wave & 1) * 64;

  floatx4 acc[4][4];
#pragma unroll
  for (int i = 0; i < 4; i++)
#pragma unroll
    for (int j = 0; j < 4; j++) acc[i][j] = (floatx4){0.f, 0.f, 0.f, 0.f};

  // async staging geometry: per wave, 4 chunks of 1 KiB each per tile.
  const int srow = (lane >> 3);        // 0..7
  const int scol8 = (lane & 7) * 8;    // elem offset of this lane's 16B chunk
  const unsigned short* ApH = nullptr;
  const float* ApF = nullptr;
  if constexpr (XPRE) {
    ApH = Xb + (long)z * M_ROWS * XSTR;
  } else {
    ApF = (z == 0) ? Xq : ((z == 1) ? Xk : Xv);
  }

  for (int k0 = 0; k0 < GK; k0 += 64) {
    __syncthreads();  // all waves done reading previous tile
    if constexpr (XPRE) {
#pragma unroll
      for (int i = 0; i < 4; i++) {
        const int row = wave * 32 + i * 8;
        async_lds16(ApH + (long)(r0 + row + srow) * XSTR + k0 + scol8,
                    As + row * 64);
        async_lds16(W + (long)(n0 + row + srow) * XSTR + k0 + scol8,
                    Bs + row * 64);
      }
    } else {
      // A: register-stage fp32 -> bf16 (32 elems/thread), B: async
      const int arow = tid >> 1;
      const int acol = (tid & 1) * 32;
      unsigned short ua[32] __attribute__((aligned(16)));
      float fa[32] __attribute__((aligned(16)));
#pragma unroll
      for (int c = 0; c < 8; c++)
        *(float4*)(fa + c * 4) = *(const float4*)(ApF + (long)(r0 + arow) * GK + k0 + acol + c * 4);
#pragma unroll
      for (int j = 0; j < 32; j++) ua[j] = f32_to_bf16(fa[j]);
      *(float4*)(As + arow * 64 + acol) = *(float4*)(ua);
      *(float4*)(As + arow * 64 + acol + 8) = *(float4*)(ua + 8);
      *(float4*)(As + arow * 64 + acol + 16) = *(float4*)(ua + 16);
      *(float4*)(As + arow * 64 + acol + 24) = *(float4*)(ua + 24);
#pragma unroll
      for (int i = 0; i < 4; i++) {
        const int row = wave * 32 + i * 8;
        async_lds16(W + (long)(n0 + row + srow) * XSTR + k0 + scol8,
                    Bs + row * 64);
      }
    }
    __syncthreads();  // vmcnt(0)+lgkmcnt(0) drain happens here

#pragma unroll
    for (int ks = 0; ks < 64; ks += 32) {
      bf16x8 af[4], bfr[4];
#pragma unroll
      for (int mt = 0; mt < 4; mt++)
        af[mt] = *(const bf16x8*)(As + (wm + mt * 16 + ln) * 64 + ks + quad * 8);
#pragma unroll
      for (int nt = 0; nt < 4; nt++)
        bfr[nt] = *(const bf16x8*)(Bs + (wn + nt * 16 + ln) * 64 + ks + quad * 8);
#pragma unroll
      for (int mt = 0; mt < 4; mt++)
#pragma unroll
        for (int nt = 0; nt < 4; nt++)
          acc[mt][nt] = __builtin_amdgcn_mfma_f32_16x16x32_bf16(af[mt], bfr[nt], acc[mt][nt], 0, 0, 0);
    }
  }

#pragma unroll
  for (int nt = 0; nt < 4; nt++) {
    const int n = n0 + wn + nt * 16 + ln;
    const float bv = bias[n];
#pragma unroll
    for (int mt = 0; mt < 4; mt++) {
      const int r = r0 + wm + mt * 16 + quad * 4;
      if (z == 2) {  // V^T: Yvt[n][r..r+3]
        u16x4 pk;
#pragma unroll
        for (int reg = 0; reg < 4; reg++) pk[reg] = f32_to_bf16(acc[mt][nt][reg] + bv);
        *(u16x4*)(Yvt + (long)n * VSTR + r) = pk;
      } else if (z == 0) {  // Q pre-scaled for exp2-domain softmax
#pragma unroll
        for (int reg = 0; reg < 4; reg++)
          Yq[(long)(r + reg) * XSTR + n] = f32_to_bf16((acc[mt][nt][reg] + bv) * QSCALE);
      } else {
#pragma unroll
        for (int reg = 0; reg < 4; reg++)
          Yk[(long)(r + reg) * XSTR + n] = f32_to_bf16(acc[mt][nt][reg] + bv);
      }
    }
  }
}

// ---------------------------------------------------------------------------
// Out projection: Y fp32 = AO(bf16,[4096][XSTR]) @ Wo(bf16,[1024][XSTR])^T + b.
// 64x128 tile, BK=64, async staging into linear LDS.
// ---------------------------------------------------------------------------
__global__ __launch_bounds__(256, 3) void out_gemm(
    const unsigned short* __restrict__ X,
    const unsigned short* __restrict__ W,
    const float* __restrict__ bias,
    float* __restrict__ Y) {
  __shared__ __align__(16) unsigned short As[64 * 64];    // linear, stride 64
  __shared__ __align__(16) unsigned short Bs[128 * 64];

  const int r0 = blockIdx.x * 64;
  const int n0 = blockIdx.y * 128;
  const int tid = threadIdx.x;
  const int lane = tid & 63;
  const int wave = tid >> 6;
  const int quad = lane >> 4;
  const int ln = lane & 15;
  const int wm = (wave >> 1) * 32;
  const int wn = (wave & 1) * 64;

  floatx4 acc[2][4];
#pragma unroll
  for (int i = 0; i < 2; i++)
#pragma unroll
    for (int j = 0; j < 4; j++) acc[i][j] = (floatx4){0.f, 0.f, 0.f, 0.f};

  const int srow = (lane >> 3);
  const int scol8 = (lane & 7) * 8;

  for (int k0 = 0; k0 < GK; k0 += 64) {
    __syncthreads();
    // A tile 64x64 = 8 KiB = 2 chunks/wave; B tile 128x64 = 4 chunks/wave
#pragma unroll
    for (int i = 0; i < 2; i++) {
      const int row = wave * 16 + i * 8;
      async_lds16(X + (long)(r0 + row + srow) * XSTR + k0 + scol8, As + row * 64);
    }
#pragma unroll
    for (int i = 0; i < 4; i++) {
      const int row = wave * 32 + i * 8;
      async_lds16(W + (long)(n0 + row + srow) * XSTR + k0 + scol8, Bs + row * 64);
    }
    __syncthreads();

#pragma unroll
    for (int ks = 0; ks < 64; ks += 32) {
      bf16x8 af[2], bfr[4];
#pragma unroll
      for (int mt = 0; mt < 2; mt++)
        af[mt] = *(const bf16x8*)(As + (wm + mt * 16 + ln) * 64 + ks + quad * 8);
#pragma unroll
      for (int nt = 0; nt < 4; nt++)
        bfr[nt] = *(const bf16x8*)(Bs + (wn + nt * 16 + ln) * 64 + ks + quad * 8);
#pragma unroll
      for (int mt = 0; mt < 2; mt++)
#pragma unroll
        for (int nt = 0; nt < 4; nt++)
          acc[mt][nt] = __builtin_amdgcn_mfma_f32_16x16x32_bf16(af[mt], bfr[nt], acc[mt][nt], 0, 0, 0);
    }
  }

#pragma unroll
  for (int nt = 0; nt < 4; nt++) {
    const int n = n0 + wn + nt * 16 + ln;
    const float bv = bias[n];
#pragma unroll
    for (int mt = 0; mt < 2; mt++) {
      const int r = r0 + wm + mt * 16 + quad * 4;
#pragma unroll
      for (int reg = 0; reg < 4; reg++)
        Y[(long)(r + reg) * GN + n] = acc[mt][nt][reg] + bv;
    }
  }
}

// ---------------------------------------------------------------------------
// Register-lean single-strip flash attention (causal), exp2-domain.
// One wave = one 16-row Q strip; KVBLK=32 per iteration.
// K frags (16 VGPR) die before V frags (16 VGPR) load: low peak pressure ->
// high residency (target ~75 VGPR => ~11-13 waves/CU by the 850/VGPR law).
// Longest strips dispatch first; x-major keeps co-resident blocks on the
// same (b,h) for K/V L1/L2 reuse.
// ---------------------------------------------------------------------------
#define PB_STR 40  // 16 q-rows x 32 kv + 8 pad (80 B rows: 2-way bank alias, free)

__global__ __launch_bounds__(64, 6) void attn_causal(
    const unsigned short* __restrict__ Q,   // bf16 [4096][XSTR], pre-scaled
    const unsigned short* __restrict__ K,   // bf16 [4096][XSTR]
    const unsigned short* __restrict__ Vt,  // bf16 [1024][VSTR]
    unsigned short* __restrict__ O) {       // bf16 [4096][XSTR]
  __shared__ __align__(16) unsigned short Pb[16 * PB_STR];

  const int s = 127 - blockIdx.x;  // strip 0..127, longest first
  const int bh = blockIdx.y;       // 0..31
  const int b = bh >> 4;
  const int h = bh & 15;

  const int lane = threadIdx.x;
  const int quad = lane >> 4;
  const int ln = lane & 15;

  const int q0 = s * 16;
  const int nkt = (s >> 1) + 1;    // number of 32-kv tiles

  const unsigned short* Qb = Q + (long)b * S_LEN * XSTR + h * D_HEAD;
  const unsigned short* Kb = K + (long)b * S_LEN * XSTR + h * D_HEAD;
  const unsigned short* Vb = Vt + (long)h * D_HEAD * VSTR + b * S_LEN;

  bf16x8 qf0 = *(const bf16x8*)(Qb + (long)(q0 + ln) * XSTR + quad * 8);
  bf16x8 qf1 = *(const bf16x8*)(Qb + (long)(q0 + ln) * XSTR + 32 + quad * 8);

  float m = -1e30f, l = 0.f;
  floatx4 o0 = (floatx4){0.f, 0.f, 0.f, 0.f};
  floatx4 o1 = (floatx4){0.f, 0.f, 0.f, 0.f};
  floatx4 o2 = (floatx4){0.f, 0.f, 0.f, 0.f};
  floatx4 o3 = (floatx4){0.f, 0.f, 0.f, 0.f};

  // per-lane base offsets (reused every iter; kv0 advances are uniform)
  const unsigned short* kRow = Kb + (long)ln * XSTR + quad * 8;        // + kv*XSTR
  const unsigned short* vRow = Vb + (long)ln * VSTR + quad * 8;        // + nt*16*VSTR + kv0

#pragma unroll 1
  for (int kt = 0; kt < nkt; kt++) {
    const int kv0 = kt * 32;

    // ---- QK^T: scores for kv0..kv0+31 (K frags die after these 4 MFMA) ----
    bf16x8 k00 = *(const bf16x8*)(kRow + (long)kv0 * XSTR);
    bf16x8 k01 = *(const bf16x8*)(kRow + (long)kv0 * XSTR + 32);
    bf16x8 k10 = *(const bf16x8*)(kRow + (long)(kv0 + 16) * XSTR);
    bf16x8 k11 = *(const bf16x8*)(kRow + (long)(kv0 + 16) * XSTR + 32);
    floatx4 s0 = (floatx4){0.f, 0.f, 0.f, 0.f};
    floatx4 s1 = (floatx4){0.f, 0.f, 0.f, 0.f};
    s0 = __builtin_amdgcn_mfma_f32_16x16x32_bf16(k00, qf0, s0, 0, 0, 0);
    s0 = __builtin_amdgcn_mfma_f32_16x16x32_bf16(k01, qf1, s0, 0, 0, 0);
    s1 = __builtin_amdgcn_mfma_f32_16x16x32_bf16(k10, qf0, s1, 0, 0, 0);
    s1 = __builtin_amdgcn_mfma_f32_16x16x32_bf16(k11, qf1, s1, 0, 0, 0);

    // ---- V loads issue here (consumed after softmax) ----
    bf16x8 v0 = *(const bf16x8*)(vRow + kv0);
    bf16x8 v1 = *(const bf16x8*)(vRow + 16 * VSTR + kv0);
    bf16x8 v2 = *(const bf16x8*)(vRow + 32 * VSTR + kv0);
    bf16x8 v3 = *(const bf16x8*)(vRow + 48 * VSTR + kv0);

    // ---- online softmax over 8 scores (exp2 domain, Q pre-scaled) ----
    float tmax = -1e30f;
    if (kt == nkt - 1) {  // diagonal tile: causal mask
      const int qg = q0 + ln;
      const int kvb0 = kv0 + quad * 4;
      const int kvb1 = kv0 + 16 + quad * 4;
#pragma unroll
      for (int reg = 0; reg < 4; reg++) {
        float a = s0[reg];
        if (kvb0 + reg > qg) a = -1e30f;
        s0[reg] = a;
        tmax = fmaxf(tmax, a);
        float c = s1[reg];
        if (kvb1 + reg > qg) c = -1e30f;
        s1[reg] = c;
        tmax = fmaxf(tmax, c);
      }
    } else {
#pragma unroll
      for (int reg = 0; reg < 4; reg++) {
        tmax = fmaxf(tmax, s0[reg]);
        tmax = fmaxf(tmax, s1[reg]);
      }
    }
    tmax = fmaxf(tmax, __shfl_xor(tmax, 16, 64));
    tmax = fmaxf(tmax, __shfl_xor(tmax, 32, 64));
    const float mnew = fmaxf(m, tmax);
    const float alpha = exp2f(m - mnew);
    m = mnew;

    float rsum = 0.f;
    u16x4 pk0, pk1;
#pragma unroll
    for (int reg = 0; reg < 4; reg++) {
      const float p0 = exp2f(s0[reg] - m);
      rsum += p0;
      pk0[reg] = f32_to_bf16(p0);
      const float p1 = exp2f(s1[reg] - m);
      rsum += p1;
      pk1[reg] = f32_to_bf16(p1);
    }
    *(u16x4*)(Pb + ln * PB_STR + quad * 4) = pk0;
    *(u16x4*)(Pb + ln * PB_STR + 16 + quad * 4) = pk1;
    rsum += __shfl_xor(rsum, 16, 64);
    rsum += __shfl_xor(rsum, 32, 64);
    l = l * alpha + rsum;
#pragma unroll
    for (int reg = 0; reg < 4; reg++) {
      o0[reg] *= alpha; o1[reg] *= alpha; o2[reg] *= alpha; o3[reg] *= alpha;
    }

    __builtin_amdgcn_wave_barrier();

    // ---- PV: quad-transpose P via LDS, one K=32 MFMA per d-tile ----
    bf16x8 p = *(const bf16x8*)(Pb + ln * PB_STR + quad * 8);
    o0 = __builtin_amdgcn_mfma_f32_16x16x32_bf16(v0, p, o0, 0, 0, 0);
    o1 = __builtin_amdgcn_mfma_f32_16x16x32_bf16(v1, p, o1, 0, 0, 0);
    o2 = __builtin_amdgcn_mfma_f32_16x16x32_bf16(v2, p, o2, 0, 0, 0);
    o3 = __builtin_amdgcn_mfma_f32_16x16x32_bf16(v3, p, o3, 0, 0, 0);

    __builtin_amdgcn_wave_barrier();
  }

  // ---- epilogue: O[q0+ln][h*64 + nt*16 + quad*4 + reg] ----
  const float inv = 1.0f / l;
  unsigned short* op = O + (long)b * S_LEN * XSTR + (long)(q0 + ln) * XSTR + h * D_HEAD;
  u16x4 w0, w1, w2, w3;
#pragma unroll
  for (int reg = 0; reg < 4; reg++) {
    w0[reg] = f32_to_bf16(o0[reg] * inv);
    w1[reg] = f32_to_bf16(o1[reg] * inv);
    w2[reg] = f32_to_bf16(o2[reg] * inv);
    w3[reg] = f32_to_bf16(o3[reg] * inv);
  }
  *(u16x4*)(op + quad * 4) = w0;
  *(u16x4*)(op + 16 + quad * 4) = w1;
  *(u16x4*)(op + 32 + quad * 4) = w2;
  *(u16x4*)(op + 48 + quad * 4) = w3;
}

// ---------------------------------------------------------------------------
extern "C" void kernel_launch(void* const* d_in, const int* in_sizes, int n_in,
                              void* d_out, int out_size, void* d_ws, size_t ws_size,
                              hipStream_t stream) {
  const float* q = (const float*)d_in[0];
  const float* k = (const float*)d_in[1];
  const float* v = (const float*)d_in[2];
  // d_in[3] = causal mask (hardcoded)
  const float* w_q = (const float*)d_in[4];
  const float* b_q = (const float*)d_in[5];
  const float* w_k = (const float*)d_in[6];
  const float* b_k = (const float*)d_in[7];
  const float* w_v = (const float*)d_in[8];
  const float* b_v = (const float*)d_in[9];
  const float* w_o = (const float*)d_in[10];
  const float* b_o = (const float*)d_in[11];
  float* out = (float*)d_out;

  unsigned short* ws = (unsigned short*)d_ws;
  const long NR = (long)M_ROWS * XSTR;        // padded [4096][1088]
  const long NV = (long)1024 * VSTR;          // padded Vt
  const long NWALL = (long)4 * 1024 * XSTR;   // 4 weight mats
  const long NXALL = 3 * NR;                  // 3 inputs
  const long TOT_XPRE = 2 * NR + NV + NWALL + NXALL;
  const bool xpre = (ws_size >= (size_t)TOT_XPRE * sizeof(unsigned short));

  unsigned short *Qp, *Kp, *Vpt, *AO, *Wb, *Xb;
  if (xpre) {
    Qp = ws;                      // [0, NR)
    Kp = ws + NR;                 // [NR, 2NR)
    Vpt = ws + 2 * NR;            // [2NR, 2NR+NV)
    Wb = ws + 2 * NR + NV;        // 4 x [1024][XSTR]
    Xb = Wb + NWALL;              // 3 x [4096][XSTR]
    AO = Xb;                      // aliases Xb (dead after qkv_gemm)
  } else {
    Qp = ws;
    Kp = ws + NR;
    Vpt = ws + 2 * NR;
    AO = ws + 2 * NR + NV;
    Wb = AO + NR;
    Xb = nullptr;
  }

  cvt_w<<<dim3(1024, 4), 256, 0, stream>>>(w_q, w_k, w_v, w_o, Wb);
  if (xpre) {
    cvt_x<<<dim3(4096, 3), 256, 0, stream>>>(q, k, v, Xb);
    qkv_gemm<true><<<dim3(M_ROWS / 128, GN / 128, 3), 256, 0, stream>>>(
        q, k, v, Xb, Wb, b_q, b_k, b_v, Qp, Kp, Vpt);
  } else {
    qkv_gemm<false><<<dim3(M_ROWS / 128, GN / 128, 3), 256, 0, stream>>>(
        q, k, v, nullptr, Wb, b_q, b_k, b_v, Qp, Kp, Vpt);
  }
  attn_causal<<<dim3(128, 32), 64, 0, stream>>>(Qp, Kp, Vpt, AO);
  out_gemm<<<dim3(M_ROWS / 64, GN / 128), 256, 0, stream>>>(AO, Wb + 3 * (long)1024 * XSTR, b_o, out);
}

// Round 6
// 278.336 us; speedup vs baseline: 1.5043x; 1.5043x over previous
//
#include <hip/hip_runtime.h>

// ---------------------------------------------------------------------------
// MultiHeadAttentionBlock: B=2, S=2048, D=1024, H=16, DK=64, causal.
// FP32 I/O; bf16 MFMA compute, fp32 accumulate.
// r12: structural attn rewrite: 4-wave blocks share K/V through LDS
//      (global_load_lds, double-buffered, XOR-swizzled source+read per rule
//      #21; involution slot^(row&7) -> 2-way read conflict = free).
//      Per-wave 16-row strip compute identical to r6 (proven); only the K/V
//      fragment source changed global->LDS.  Evidence: r6/r8/r11 all pin
//      ~1000 cyc/iter/CU regardless of decomposition (structural plateau,
//      = documented m185 167-TF plateau); dominant removable term is the
//      8x-duplicated per-wave K/V gather.
//      GEMMs/cvt identical to r10.
// ---------------------------------------------------------------------------

typedef __attribute__((ext_vector_type(8))) short bf16x8;     // 8 bf16 = 4 VGPRs
typedef __attribute__((ext_vector_type(4))) float floatx4;    // MFMA C/D
typedef __attribute__((ext_vector_type(4))) unsigned short u16x4;  // 8B packed bf16

#define S_LEN 2048
#define D_MODEL 1024
#define N_HEADS 16
#define D_HEAD 64
#define M_ROWS 4096   // B*S
#define QSCALE 0.18033688011112042f  // 0.125 * log2(e)

#define XSTR 1088   // padded row stride (elems) for [*,1024] bf16 buffers
#define VSTR 4160   // padded row stride (elems) for Vt [1024][4096]

__device__ __forceinline__ unsigned short f32_to_bf16(float f) {
  unsigned int u = __builtin_bit_cast(unsigned int, f);
  u += 0x7FFFu + ((u >> 16) & 1u);  // RNE
  return (unsigned short)(u >> 16);
}

// async 16B global->LDS copy: LDS dest is wave-uniform base + lane*16.
__device__ __forceinline__ void async_lds16(const unsigned short* g, unsigned short* l) {
  __builtin_amdgcn_global_load_lds(
      (const __attribute__((address_space(1))) unsigned int*)g,
      (__attribute__((address_space(3))) unsigned int*)l, 16, 0, 0);
}

// ---------------------------------------------------------------------------
// fp32 -> bf16 pre-passes (row-per-block, writing padded rows).
// ---------------------------------------------------------------------------
__global__ __launch_bounds__(256) void cvt_w(
    const float* __restrict__ w0, const float* __restrict__ w1,
    const float* __restrict__ w2, const float* __restrict__ w3,
    unsigned short* __restrict__ dst) {
  const int row = blockIdx.x;       // 0..1023
  const int z = blockIdx.y;         // 0..3
  const float* src = ((z == 0) ? w0 : (z == 1) ? w1 : (z == 2) ? w2 : w3) + (long)row * 1024;
  unsigned short* d = dst + (long)z * 1024 * XSTR + (long)row * XSTR;
  const int tid = threadIdx.x;
  float4 f = ((const float4*)src)[tid];
  u16x4 o;
  o[0] = f32_to_bf16(f.x); o[1] = f32_to_bf16(f.y);
  o[2] = f32_to_bf16(f.z); o[3] = f32_to_bf16(f.w);
  *(u16x4*)(d + tid * 4) = o;
}

__global__ __launch_bounds__(256) void cvt_x(
    const float* __restrict__ x0, const float* __restrict__ x1,
    const float* __restrict__ x2, unsigned short* __restrict__ dst) {
  const int row = blockIdx.x;       // 0..4095
  const int z = blockIdx.y;         // 0..2
  const float* src = ((z == 0) ? x0 : (z == 1) ? x1 : x2) + (long)row * 1024;
  unsigned short* d = dst + (long)z * M_ROWS * XSTR + (long)row * XSTR;
  const int tid = threadIdx.x;
  float4 f = ((const float4*)src)[tid];
  u16x4 o;
  o[0] = f32_to_bf16(f.x); o[1] = f32_to_bf16(f.y);
  o[2] = f32_to_bf16(f.z); o[3] = f32_to_bf16(f.w);
  *(u16x4*)(d + tid * 4) = o;
}

// ---------------------------------------------------------------------------
// Fused QKV projection. z = blockIdx.z.  Y = X @ W^T + b.
// 128x128 tile, BK=64, 4 waves x (64x64).  global_load_lds staging into
// linear [128][64] LDS, 2 barriers per K-step.  All bf16 operands padded.
// z=0: Y = (X Wq^T + bq) * QSCALE.  z=1: plain.  z=2: Y^T (V transposed).
// ---------------------------------------------------------------------------
#define GK 1024
#define GN 1024

template <bool XPRE>
__global__ __launch_bounds__(256, 3) void qkv_gemm(
    const float* __restrict__ Xq, const float* __restrict__ Xk, const float* __restrict__ Xv,
    const unsigned short* __restrict__ Xb,  // bf16, 3 x [4096][XSTR] (XPRE only)
    const unsigned short* __restrict__ Wb,  // bf16, 4 x [1024][XSTR]: [wq|wk|wv|wo]
    const float* __restrict__ bq, const float* __restrict__ bk, const float* __restrict__ bv,
    unsigned short* __restrict__ Yq, unsigned short* __restrict__ Yk,
    unsigned short* __restrict__ Yvt) {
  __shared__ __align__(16) unsigned short As[128 * 64];  // linear, stride 64
  __shared__ __align__(16) unsigned short Bs[128 * 64];

  const int z = blockIdx.z;
  const unsigned short* W = Wb + (long)z * 1024 * XSTR;
  const float* bias = (z == 0) ? bq : ((z == 1) ? bk : bv);

  const int r0 = blockIdx.x * 128;
  const int n0 = blockIdx.y * 128;
  const int tid = threadIdx.x;
  const int lane = tid & 63;
  const int wave = tid >> 6;
  const int quad = lane >> 4;
  const int ln = lane & 15;
  const int wm = (wave >> 1) * 64;
  const int wn = (wave & 1) * 64;

  floatx4 acc[4][4];
#pragma unroll
  for (int i = 0; i < 4; i++)
#pragma unroll
    for (int j = 0; j < 4; j++) acc[i][j] = (floatx4){0.f, 0.f, 0.f, 0.f};

  // async staging geometry: per wave, 4 chunks of 1 KiB each per tile.
  const int srow = (lane >> 3);        // 0..7
  const int scol8 = (lane & 7) * 8;    // elem offset of this lane's 16B chunk
  const unsigned short* ApH = nullptr;
  const float* ApF = nullptr;
  if constexpr (XPRE) {
    ApH = Xb + (long)z * M_ROWS * XSTR;
  } else {
    ApF = (z == 0) ? Xq : ((z == 1) ? Xk : Xv);
  }

  for (int k0 = 0; k0 < GK; k0 += 64) {
    __syncthreads();  // all waves done reading previous tile
    if constexpr (XPRE) {
#pragma unroll
      for (int i = 0; i < 4; i++) {
        const int row = wave * 32 + i * 8;
        async_lds16(ApH + (long)(r0 + row + srow) * XSTR + k0 + scol8,
                    As + row * 64);
        async_lds16(W + (long)(n0 + row + srow) * XSTR + k0 + scol8,
                    Bs + row * 64);
      }
    } else {
      // A: register-stage fp32 -> bf16 (32 elems/thread), B: async
      const int arow = tid >> 1;
      const int acol = (tid & 1) * 32;
      unsigned short ua[32] __attribute__((aligned(16)));
      float fa[32] __attribute__((aligned(16)));
#pragma unroll
      for (int c = 0; c < 8; c++)
        *(float4*)(fa + c * 4) = *(const float4*)(ApF + (long)(r0 + arow) * GK + k0 + acol + c * 4);
#pragma unroll
      for (int j = 0; j < 32; j++) ua[j] = f32_to_bf16(fa[j]);
      *(float4*)(As + arow * 64 + acol) = *(float4*)(ua);
      *(float4*)(As + arow * 64 + acol + 8) = *(float4*)(ua + 8);
      *(float4*)(As + arow * 64 + acol + 16) = *(float4*)(ua + 16);
      *(float4*)(As + arow * 64 + acol + 24) = *(float4*)(ua + 24);
#pragma unroll
      for (int i = 0; i < 4; i++) {
        const int row = wave * 32 + i * 8;
        async_lds16(W + (long)(n0 + row + srow) * XSTR + k0 + scol8,
                    Bs + row * 64);
      }
    }
    __syncthreads();  // vmcnt(0)+lgkmcnt(0) drain happens here

#pragma unroll
    for (int ks = 0; ks < 64; ks += 32) {
      bf16x8 af[4], bfr[4];
#pragma unroll
      for (int mt = 0; mt < 4; mt++)
        af[mt] = *(const bf16x8*)(As + (wm + mt * 16 + ln) * 64 + ks + quad * 8);
#pragma unroll
      for (int nt = 0; nt < 4; nt++)
        bfr[nt] = *(const bf16x8*)(Bs + (wn + nt * 16 + ln) * 64 + ks + quad * 8);
#pragma unroll
      for (int mt = 0; mt < 4; mt++)
#pragma unroll
        for (int nt = 0; nt < 4; nt++)
          acc[mt][nt] = __builtin_amdgcn_mfma_f32_16x16x32_bf16(af[mt], bfr[nt], acc[mt][nt], 0, 0, 0);
    }
  }

#pragma unroll
  for (int nt = 0; nt < 4; nt++) {
    const int n = n0 + wn + nt * 16 + ln;
    const float bv = bias[n];
#pragma unroll
    for (int mt = 0; mt < 4; mt++) {
      const int r = r0 + wm + mt * 16 + quad * 4;
      if (z == 2) {  // V^T: Yvt[n][r..r+3]
        u16x4 pk;
#pragma unroll
        for (int reg = 0; reg < 4; reg++) pk[reg] = f32_to_bf16(acc[mt][nt][reg] + bv);
        *(u16x4*)(Yvt + (long)n * VSTR + r) = pk;
      } else if (z == 0) {  // Q pre-scaled for exp2-domain softmax
#pragma unroll
        for (int reg = 0; reg < 4; reg++)
          Yq[(long)(r + reg) * XSTR + n] = f32_to_bf16((acc[mt][nt][reg] + bv) * QSCALE);
      } else {
#pragma unroll
        for (int reg = 0; reg < 4; reg++)
          Yk[(long)(r + reg) * XSTR + n] = f32_to_bf16(acc[mt][nt][reg] + bv);
      }
    }
  }
}

// ---------------------------------------------------------------------------
// Out projection: Y fp32 = AO(bf16,[4096][XSTR]) @ Wo(bf16,[1024][XSTR])^T + b.
// 64x128 tile, BK=64, async staging into linear LDS.
// ---------------------------------------------------------------------------
__global__ __launch_bounds__(256, 3) void out_gemm(
    const unsigned short* __restrict__ X,
    const unsigned short* __restrict__ W,
    const float* __restrict__ bias,
    float* __restrict__ Y) {
  __shared__ __align__(16) unsigned short As[64 * 64];    // linear, stride 64
  __shared__ __align__(16) unsigned short Bs[128 * 64];

  const int r0 = blockIdx.x * 64;
  const int n0 = blockIdx.y * 128;
  const int tid = threadIdx.x;
  const int lane = tid & 63;
  const int wave = tid >> 6;
  const int quad = lane >> 4;
  const int ln = lane & 15;
  const int wm = (wave >> 1) * 32;
  const int wn = (wave & 1) * 64;

  floatx4 acc[2][4];
#pragma unroll
  for (int i = 0; i < 2; i++)
#pragma unroll
    for (int j = 0; j < 4; j++) acc[i][j] = (floatx4){0.f, 0.f, 0.f, 0.f};

  const int srow = (lane >> 3);
  const int scol8 = (lane & 7) * 8;

  for (int k0 = 0; k0 < GK; k0 += 64) {
    __syncthreads();
    // A tile 64x64 = 8 KiB = 2 chunks/wave; B tile 128x64 = 4 chunks/wave
#pragma unroll
    for (int i = 0; i < 2; i++) {
      const int row = wave * 16 + i * 8;
      async_lds16(X + (long)(r0 + row + srow) * XSTR + k0 + scol8, As + row * 64);
    }
#pragma unroll
    for (int i = 0; i < 4; i++) {
      const int row = wave * 32 + i * 8;
      async_lds16(W + (long)(n0 + row + srow) * XSTR + k0 + scol8, Bs + row * 64);
    }
    __syncthreads();

#pragma unroll
    for (int ks = 0; ks < 64; ks += 32) {
      bf16x8 af[2], bfr[4];
#pragma unroll
      for (int mt = 0; mt < 2; mt++)
        af[mt] = *(const bf16x8*)(As + (wm + mt * 16 + ln) * 64 + ks + quad * 8);
#pragma unroll
      for (int nt = 0; nt < 4; nt++)
        bfr[nt] = *(const bf16x8*)(Bs + (wn + nt * 16 + ln) * 64 + ks + quad * 8);
#pragma unroll
      for (int mt = 0; mt < 2; mt++)
#pragma unroll
        for (int nt = 0; nt < 4; nt++)
          acc[mt][nt] = __builtin_amdgcn_mfma_f32_16x16x32_bf16(af[mt], bfr[nt], acc[mt][nt], 0, 0, 0);
    }
  }

#pragma unroll
  for (int nt = 0; nt < 4; nt++) {
    const int n = n0 + wn + nt * 16 + ln;
    const float bv = bias[n];
#pragma unroll
    for (int mt = 0; mt < 2; mt++) {
      const int r = r0 + wm + mt * 16 + quad * 4;
#pragma unroll
      for (int reg = 0; reg < 4; reg++)
        Y[(long)(r + reg) * GN + n] = acc[mt][nt][reg] + bv;
    }
  }
}

// ---------------------------------------------------------------------------
// Shared-KV LDS flash attention (causal), exp2-domain.
// Block = 4 waves (256 thr); wave w owns 16-row strip s = 4*jg + w.
// K tile [64kv][64d] and V^T tile [64d][64kv] staged once per block per kt
// via global_load_lds (2+2 chunks/thread), double-buffered.
// Swizzle (rule #21): linear LDS dest + swizzled global SOURCE slot
// (slot^(row&7)) + same swizzle on ds_read -> 2-way conflict (free).
// Per-wave compute = r6's proven strip code (QK, softmax, mask, P-LDS, PV).
// ---------------------------------------------------------------------------
#define PSTR 72

__global__ __launch_bounds__(256, 3) void attn_causal(
    const unsigned short* __restrict__ Q,   // bf16 [4096][XSTR], pre-scaled
    const unsigned short* __restrict__ K,   // bf16 [4096][XSTR]
    const unsigned short* __restrict__ Vt,  // bf16 [1024][VSTR]
    unsigned short* __restrict__ O) {       // bf16 [4096][XSTR]
  __shared__ __align__(16) unsigned short Ks[2][64 * 64];  // [kv][d], swz slots
  __shared__ __align__(16) unsigned short Vs[2][64 * 64];  // [d][kv], swz slots
  __shared__ __align__(16) unsigned short Pb[4][16 * PSTR];

  const int jg = 31 - blockIdx.x;  // strip group, longest first
  const int bh = blockIdx.y;       // 0..31
  const int b = bh >> 4;
  const int h = bh & 15;

  const int tid = threadIdx.x;
  const int wave = tid >> 6;       // 0..3
  const int lane = tid & 63;
  const int quad = lane >> 4;
  const int ln = lane & 15;

  const int s = jg * 4 + wave;     // strip 0..127
  const int q0 = s * 16;
  const int nkt_self = (s >> 2) + 1;   // = jg+1 for all waves' block bound
  const int nkt_blk = jg + 1;          // ((4jg+3)>>2)+1

  const unsigned short* Qb = Q + (long)b * S_LEN * XSTR + h * D_HEAD;
  const unsigned short* Kb = K + (long)b * S_LEN * XSTR + h * D_HEAD;
  const unsigned short* Vb = Vt + (long)h * D_HEAD * VSTR + b * S_LEN;

  // staging source (per thread): row = tid>>3 (0..31, +32 for 2nd chunk),
  // source slot pre-swizzled so linear LDS holds swizzled layout.
  const int srow = tid >> 3;
  const int sslot = (tid & 7) ^ (srow & 7);   // (row+32)&7 == row&7
  const unsigned short* Ksrc = Kb + (long)srow * XSTR + sslot * 8;
  const unsigned short* Vsrc = Vb + (long)srow * VSTR + sslot * 8;
  unsigned short* myP = Pb[wave];
  const int swz = ln & 7;  // row&7 for rows ct*16+ln (16 ≡ 0 mod 8)

  auto stage = [&](int buf, int kt) {
    const long kOff = (long)(kt * 64) * XSTR;
    const int vOff = kt * 64;
    async_lds16(Ksrc + kOff, &Ks[buf][wave * 512]);
    async_lds16(Ksrc + kOff + (long)32 * XSTR, &Ks[buf][2048 + wave * 512]);
    async_lds16(Vsrc + vOff, &Vs[buf][wave * 512]);
    async_lds16(Vsrc + (long)32 * VSTR + vOff, &Vs[buf][2048 + wave * 512]);
  };

  // Q fragments (held in registers for the whole kernel)
  bf16x8 qf0 = *(const bf16x8*)(Qb + (long)(q0 + ln) * XSTR + quad * 8);
  bf16x8 qf1 = *(const bf16x8*)(Qb + (long)(q0 + ln) * XSTR + 32 + quad * 8);

  float m = -1e30f, l = 0.f;
  floatx4 o[4];
#pragma unroll
  for (int nt = 0; nt < 4; nt++) o[nt] = (floatx4){0.f, 0.f, 0.f, 0.f};

  auto iterate = [&](int buf, int kt) {
    const int kv0 = kt * 64;
    const unsigned short* Kt = Ks[buf];
    const unsigned short* Vtile = Vs[buf];

    // ---- QK^T from LDS (swizzled read) ----
    floatx4 sS[4];
#pragma unroll
    for (int ct = 0; ct < 4; ct++) {
      const int row = ct * 16 + ln;
      bf16x8 k0 = *(const bf16x8*)(Kt + row * 64 + ((quad ^ swz) * 8));
      bf16x8 k1 = *(const bf16x8*)(Kt + row * 64 + (((4 + quad) ^ swz) * 8));
      sS[ct] = (floatx4){0.f, 0.f, 0.f, 0.f};
      sS[ct] = __builtin_amdgcn_mfma_f32_16x16x32_bf16(k0, qf0, sS[ct], 0, 0, 0);
      sS[ct] = __builtin_amdgcn_mfma_f32_16x16x32_bf16(k1, qf1, sS[ct], 0, 0, 0);
    }

    // ---- online softmax (exp2 domain; Q pre-scaled) ----
    float tmax = -1e30f;
    if (kt == nkt_self - 1) {  // diagonal tile: causal mask
      const int qg = q0 + ln;
#pragma unroll
      for (int ct = 0; ct < 4; ct++) {
        const int kvb = kv0 + ct * 16 + quad * 4;
#pragma unroll
        for (int reg = 0; reg < 4; reg++) {
          float sv = sS[ct][reg];
          if (kvb + reg > qg) sv = -1e30f;
          sS[ct][reg] = sv;
          tmax = fmaxf(tmax, sv);
        }
      }
    } else {
#pragma unroll
      for (int ct = 0; ct < 4; ct++)
#pragma unroll
        for (int reg = 0; reg < 4; reg++) tmax = fmaxf(tmax, sS[ct][reg]);
    }
    tmax = fmaxf(tmax, __shfl_xor(tmax, 16, 64));
    tmax = fmaxf(tmax, __shfl_xor(tmax, 32, 64));
    const float mnew = fmaxf(m, tmax);
    const float alpha = exp2f(m - mnew);
    m = mnew;
    float rsum = 0.f;
#pragma unroll
    for (int ct = 0; ct < 4; ct++) {
      u16x4 pk;
#pragma unroll
      for (int reg = 0; reg < 4; reg++) {
        const float p = exp2f(sS[ct][reg] - m);
        rsum += p;
        pk[reg] = f32_to_bf16(p);
      }
      *(u16x4*)(myP + ln * PSTR + ct * 16 + quad * 4) = pk;
    }
    rsum += __shfl_xor(rsum, 16, 64);
    rsum += __shfl_xor(rsum, 32, 64);
    l = l * alpha + rsum;
#pragma unroll
    for (int nt = 0; nt < 4; nt++)
#pragma unroll
      for (int reg = 0; reg < 4; reg++) o[nt][reg] *= alpha;

    __builtin_amdgcn_wave_barrier();

    // ---- PV: P via per-wave LDS transpose, V from shared LDS tile ----
    bf16x8 p0 = *(const bf16x8*)(myP + ln * PSTR + quad * 8);
    bf16x8 p1 = *(const bf16x8*)(myP + ln * PSTR + 32 + quad * 8);
#pragma unroll
    for (int nt = 0; nt < 4; nt++) {
      const int row = nt * 16 + ln;
      bf16x8 v0 = *(const bf16x8*)(Vtile + row * 64 + ((quad ^ swz) * 8));
      bf16x8 v1 = *(const bf16x8*)(Vtile + row * 64 + (((4 + quad) ^ swz) * 8));
      o[nt] = __builtin_amdgcn_mfma_f32_16x16x32_bf16(v0, p0, o[nt], 0, 0, 0);
      o[nt] = __builtin_amdgcn_mfma_f32_16x16x32_bf16(v1, p1, o[nt], 0, 0, 0);
    }
    __builtin_amdgcn_wave_barrier();
  };

  // ---- main loop: stage(kt+1) || compute(kt), one barrier per kt ----
  stage(0, 0);
  __syncthreads();  // drains vmcnt(0): tile 0 ready
#pragma unroll 1
  for (int kt = 0; kt < nkt_blk; kt++) {
    if (kt + 1 < nkt_blk) stage((kt + 1) & 1, kt + 1);
    if (kt < nkt_self) iterate(kt & 1, kt);
    __syncthreads();  // drains async loads for kt+1; guards buffer reuse
  }

  // ---- epilogue ----
  const float inv = 1.0f / l;
  unsigned short* op = O + (long)b * S_LEN * XSTR + (long)(q0 + ln) * XSTR + h * D_HEAD;
#pragma unroll
  for (int nt = 0; nt < 4; nt++) {
    u16x4 pk;
#pragma unroll
    for (int reg = 0; reg < 4; reg++) pk[reg] = f32_to_bf16(o[nt][reg] * inv);
    *(u16x4*)(op + nt * 16 + quad * 4) = pk;
  }
}

// ---------------------------------------------------------------------------
extern "C" void kernel_launch(void* const* d_in, const int* in_sizes, int n_in,
                              void* d_out, int out_size, void* d_ws, size_t ws_size,
                              hipStream_t stream) {
  const float* q = (const float*)d_in[0];
  const float* k = (const float*)d_in[1];
  const float* v = (const float*)d_in[2];
  // d_in[3] = causal mask (hardcoded)
  const float* w_q = (const float*)d_in[4];
  const float* b_q = (const float*)d_in[5];
  const float* w_k = (const float*)d_in[6];
  const float* b_k = (const float*)d_in[7];
  const float* w_v = (const float*)d_in[8];
  const float* b_v = (const float*)d_in[9];
  const float* w_o = (const float*)d_in[10];
  const float* b_o = (const float*)d_in[11];
  float* out = (float*)d_out;

  unsigned short* ws = (unsigned short*)d_ws;
  const long NR = (long)M_ROWS * XSTR;        // padded [4096][1088]
  const long NV = (long)1024 * VSTR;          // padded Vt
  const long NWALL = (long)4 * 1024 * XSTR;   // 4 weight mats
  const long NXALL = 3 * NR;                  // 3 inputs
  const long TOT_XPRE = 2 * NR + NV + NWALL + NXALL;
  const bool xpre = (ws_size >= (size_t)TOT_XPRE * sizeof(unsigned short));

  unsigned short *Qp, *Kp, *Vpt, *AO, *Wb, *Xb;
  if (xpre) {
    Qp = ws;                      // [0, NR)
    Kp = ws + NR;                 // [NR, 2NR)
    Vpt = ws + 2 * NR;            // [2NR, 2NR+NV)
    Wb = ws + 2 * NR + NV;        // 4 x [1024][XSTR]
    Xb = Wb + NWALL;              // 3 x [4096][XSTR]
    AO = Xb;                      // aliases Xb (dead after qkv_gemm)
  } else {
    Qp = ws;
    Kp = ws + NR;
    Vpt = ws + 2 * NR;
    AO = ws + 2 * NR + NV;
    Wb = AO + NR;
    Xb = nullptr;
  }

  cvt_w<<<dim3(1024, 4), 256, 0, stream>>>(w_q, w_k, w_v, w_o, Wb);
  if (xpre) {
    cvt_x<<<dim3(4096, 3), 256, 0, stream>>>(q, k, v, Xb);
    qkv_gemm<true><<<dim3(M_ROWS / 128, GN / 128, 3), 256, 0, stream>>>(
        q, k, v, Xb, Wb, b_q, b_k, b_v, Qp, Kp, Vpt);
  } else {
    qkv_gemm<false><<<dim3(M_ROWS / 128, GN / 128, 3), 256, 0, stream>>>(
        q, k, v, nullptr, Wb, b_q, b_k, b_v, Qp, Kp, Vpt);
  }
  attn_causal<<<dim3(32, 32), 256, 0, stream>>>(Qp, Kp, Vpt, AO);
  out_gemm<<<dim3(M_ROWS / 64, GN / 128), 256, 0, stream>>>(AO, Wb + 3 * (long)1024 * XSTR, b_o, out);
}

// Round 7
// 274.721 us; speedup vs baseline: 1.5241x; 1.0132x over previous
//
#include <hip/hip_runtime.h>

// ---------------------------------------------------------------------------
// MultiHeadAttentionBlock: B=2, S=2048, D=1024, H=16, DK=64, causal.
// FP32 I/O; bf16 MFMA compute, fp32 accumulate.
// r13: balanced shared-KV attention. r12 diagnosis: block durations 1..32
//      iters starve the CU scheduler (resident = 28% of offered vs r6's 79%
//      with balanced blocks).  Fix: block g covers strips
//      {2g, 2g+1, 126-2g, 127-2g} -> every block runs nkt(127-2g) in [17,32]
//      iterations (r6's pairing at 4-wave granularity).  Short-strip waves
//      idle at barriers (free).  Staging covers the union range.
//      Everything else identical to r12 (stage/swizzle/compute/GEMMs).
// ---------------------------------------------------------------------------

typedef __attribute__((ext_vector_type(8))) short bf16x8;     // 8 bf16 = 4 VGPRs
typedef __attribute__((ext_vector_type(4))) float floatx4;    // MFMA C/D
typedef __attribute__((ext_vector_type(4))) unsigned short u16x4;  // 8B packed bf16

#define S_LEN 2048
#define D_MODEL 1024
#define N_HEADS 16
#define D_HEAD 64
#define M_ROWS 4096   // B*S
#define QSCALE 0.18033688011112042f  // 0.125 * log2(e)

#define XSTR 1088   // padded row stride (elems) for [*,1024] bf16 buffers
#define VSTR 4160   // padded row stride (elems) for Vt [1024][4096]

__device__ __forceinline__ unsigned short f32_to_bf16(float f) {
  unsigned int u = __builtin_bit_cast(unsigned int, f);
  u += 0x7FFFu + ((u >> 16) & 1u);  // RNE
  return (unsigned short)(u >> 16);
}

// async 16B global->LDS copy: LDS dest is wave-uniform base + lane*16.
__device__ __forceinline__ void async_lds16(const unsigned short* g, unsigned short* l) {
  __builtin_amdgcn_global_load_lds(
      (const __attribute__((address_space(1))) unsigned int*)g,
      (__attribute__((address_space(3))) unsigned int*)l, 16, 0, 0);
}

// ---------------------------------------------------------------------------
// fp32 -> bf16 pre-passes (row-per-block, writing padded rows).
// ---------------------------------------------------------------------------
__global__ __launch_bounds__(256) void cvt_w(
    const float* __restrict__ w0, const float* __restrict__ w1,
    const float* __restrict__ w2, const float* __restrict__ w3,
    unsigned short* __restrict__ dst) {
  const int row = blockIdx.x;       // 0..1023
  const int z = blockIdx.y;         // 0..3
  const float* src = ((z == 0) ? w0 : (z == 1) ? w1 : (z == 2) ? w2 : w3) + (long)row * 1024;
  unsigned short* d = dst + (long)z * 1024 * XSTR + (long)row * XSTR;
  const int tid = threadIdx.x;
  float4 f = ((const float4*)src)[tid];
  u16x4 o;
  o[0] = f32_to_bf16(f.x); o[1] = f32_to_bf16(f.y);
  o[2] = f32_to_bf16(f.z); o[3] = f32_to_bf16(f.w);
  *(u16x4*)(d + tid * 4) = o;
}

__global__ __launch_bounds__(256) void cvt_x(
    const float* __restrict__ x0, const float* __restrict__ x1,
    const float* __restrict__ x2, unsigned short* __restrict__ dst) {
  const int row = blockIdx.x;       // 0..4095
  const int z = blockIdx.y;         // 0..2
  const float* src = ((z == 0) ? x0 : (z == 1) ? x1 : x2) + (long)row * 1024;
  unsigned short* d = dst + (long)z * M_ROWS * XSTR + (long)row * XSTR;
  const int tid = threadIdx.x;
  float4 f = ((const float4*)src)[tid];
  u16x4 o;
  o[0] = f32_to_bf16(f.x); o[1] = f32_to_bf16(f.y);
  o[2] = f32_to_bf16(f.z); o[3] = f32_to_bf16(f.w);
  *(u16x4*)(d + tid * 4) = o;
}

// ---------------------------------------------------------------------------
// Fused QKV projection. z = blockIdx.z.  Y = X @ W^T + b.
// 128x128 tile, BK=64, 4 waves x (64x64).  global_load_lds staging into
// linear [128][64] LDS, 2 barriers per K-step.  All bf16 operands padded.
// z=0: Y = (X Wq^T + bq) * QSCALE.  z=1: plain.  z=2: Y^T (V transposed).
// ---------------------------------------------------------------------------
#define GK 1024
#define GN 1024

template <bool XPRE>
__global__ __launch_bounds__(256, 3) void qkv_gemm(
    const float* __restrict__ Xq, const float* __restrict__ Xk, const float* __restrict__ Xv,
    const unsigned short* __restrict__ Xb,  // bf16, 3 x [4096][XSTR] (XPRE only)
    const unsigned short* __restrict__ Wb,  // bf16, 4 x [1024][XSTR]: [wq|wk|wv|wo]
    const float* __restrict__ bq, const float* __restrict__ bk, const float* __restrict__ bv,
    unsigned short* __restrict__ Yq, unsigned short* __restrict__ Yk,
    unsigned short* __restrict__ Yvt) {
  __shared__ __align__(16) unsigned short As[128 * 64];  // linear, stride 64
  __shared__ __align__(16) unsigned short Bs[128 * 64];

  const int z = blockIdx.z;
  const unsigned short* W = Wb + (long)z * 1024 * XSTR;
  const float* bias = (z == 0) ? bq : ((z == 1) ? bk : bv);

  const int r0 = blockIdx.x * 128;
  const int n0 = blockIdx.y * 128;
  const int tid = threadIdx.x;
  const int lane = tid & 63;
  const int wave = tid >> 6;
  const int quad = lane >> 4;
  const int ln = lane & 15;
  const int wm = (wave >> 1) * 64;
  const int wn = (wave & 1) * 64;

  floatx4 acc[4][4];
#pragma unroll
  for (int i = 0; i < 4; i++)
#pragma unroll
    for (int j = 0; j < 4; j++) acc[i][j] = (floatx4){0.f, 0.f, 0.f, 0.f};

  // async staging geometry: per wave, 4 chunks of 1 KiB each per tile.
  const int srow = (lane >> 3);        // 0..7
  const int scol8 = (lane & 7) * 8;    // elem offset of this lane's 16B chunk
  const unsigned short* ApH = nullptr;
  const float* ApF = nullptr;
  if constexpr (XPRE) {
    ApH = Xb + (long)z * M_ROWS * XSTR;
  } else {
    ApF = (z == 0) ? Xq : ((z == 1) ? Xk : Xv);
  }

  for (int k0 = 0; k0 < GK; k0 += 64) {
    __syncthreads();  // all waves done reading previous tile
    if constexpr (XPRE) {
#pragma unroll
      for (int i = 0; i < 4; i++) {
        const int row = wave * 32 + i * 8;
        async_lds16(ApH + (long)(r0 + row + srow) * XSTR + k0 + scol8,
                    As + row * 64);
        async_lds16(W + (long)(n0 + row + srow) * XSTR + k0 + scol8,
                    Bs + row * 64);
      }
    } else {
      // A: register-stage fp32 -> bf16 (32 elems/thread), B: async
      const int arow = tid >> 1;
      const int acol = (tid & 1) * 32;
      unsigned short ua[32] __attribute__((aligned(16)));
      float fa[32] __attribute__((aligned(16)));
#pragma unroll
      for (int c = 0; c < 8; c++)
        *(float4*)(fa + c * 4) = *(const float4*)(ApF + (long)(r0 + arow) * GK + k0 + acol + c * 4);
#pragma unroll
      for (int j = 0; j < 32; j++) ua[j] = f32_to_bf16(fa[j]);
      *(float4*)(As + arow * 64 + acol) = *(float4*)(ua);
      *(float4*)(As + arow * 64 + acol + 8) = *(float4*)(ua + 8);
      *(float4*)(As + arow * 64 + acol + 16) = *(float4*)(ua + 16);
      *(float4*)(As + arow * 64 + acol + 24) = *(float4*)(ua + 24);
#pragma unroll
      for (int i = 0; i < 4; i++) {
        const int row = wave * 32 + i * 8;
        async_lds16(W + (long)(n0 + row + srow) * XSTR + k0 + scol8,
                    Bs + row * 64);
      }
    }
    __syncthreads();  // vmcnt(0)+lgkmcnt(0) drain happens here

#pragma unroll
    for (int ks = 0; ks < 64; ks += 32) {
      bf16x8 af[4], bfr[4];
#pragma unroll
      for (int mt = 0; mt < 4; mt++)
        af[mt] = *(const bf16x8*)(As + (wm + mt * 16 + ln) * 64 + ks + quad * 8);
#pragma unroll
      for (int nt = 0; nt < 4; nt++)
        bfr[nt] = *(const bf16x8*)(Bs + (wn + nt * 16 + ln) * 64 + ks + quad * 8);
#pragma unroll
      for (int mt = 0; mt < 4; mt++)
#pragma unroll
        for (int nt = 0; nt < 4; nt++)
          acc[mt][nt] = __builtin_amdgcn_mfma_f32_16x16x32_bf16(af[mt], bfr[nt], acc[mt][nt], 0, 0, 0);
    }
  }

#pragma unroll
  for (int nt = 0; nt < 4; nt++) {
    const int n = n0 + wn + nt * 16 + ln;
    const float bv = bias[n];
#pragma unroll
    for (int mt = 0; mt < 4; mt++) {
      const int r = r0 + wm + mt * 16 + quad * 4;
      if (z == 2) {  // V^T: Yvt[n][r..r+3]
        u16x4 pk;
#pragma unroll
        for (int reg = 0; reg < 4; reg++) pk[reg] = f32_to_bf16(acc[mt][nt][reg] + bv);
        *(u16x4*)(Yvt + (long)n * VSTR + r) = pk;
      } else if (z == 0) {  // Q pre-scaled for exp2-domain softmax
#pragma unroll
        for (int reg = 0; reg < 4; reg++)
          Yq[(long)(r + reg) * XSTR + n] = f32_to_bf16((acc[mt][nt][reg] + bv) * QSCALE);
      } else {
#pragma unroll
        for (int reg = 0; reg < 4; reg++)
          Yk[(long)(r + reg) * XSTR + n] = f32_to_bf16(acc[mt][nt][reg] + bv);
      }
    }
  }
}

// ---------------------------------------------------------------------------
// Out projection: Y fp32 = AO(bf16,[4096][XSTR]) @ Wo(bf16,[1024][XSTR])^T + b.
// 64x128 tile, BK=64, async staging into linear LDS.
// ---------------------------------------------------------------------------
__global__ __launch_bounds__(256, 3) void out_gemm(
    const unsigned short* __restrict__ X,
    const unsigned short* __restrict__ W,
    const float* __restrict__ bias,
    float* __restrict__ Y) {
  __shared__ __align__(16) unsigned short As[64 * 64];    // linear, stride 64
  __shared__ __align__(16) unsigned short Bs[128 * 64];

  const int r0 = blockIdx.x * 64;
  const int n0 = blockIdx.y * 128;
  const int tid = threadIdx.x;
  const int lane = tid & 63;
  const int wave = tid >> 6;
  const int quad = lane >> 4;
  const int ln = lane & 15;
  const int wm = (wave >> 1) * 32;
  const int wn = (wave & 1) * 64;

  floatx4 acc[2][4];
#pragma unroll
  for (int i = 0; i < 2; i++)
#pragma unroll
    for (int j = 0; j < 4; j++) acc[i][j] = (floatx4){0.f, 0.f, 0.f, 0.f};

  const int srow = (lane >> 3);
  const int scol8 = (lane & 7) * 8;

  for (int k0 = 0; k0 < GK; k0 += 64) {
    __syncthreads();
    // A tile 64x64 = 8 KiB = 2 chunks/wave; B tile 128x64 = 4 chunks/wave
#pragma unroll
    for (int i = 0; i < 2; i++) {
      const int row = wave * 16 + i * 8;
      async_lds16(X + (long)(r0 + row + srow) * XSTR + k0 + scol8, As + row * 64);
    }
#pragma unroll
    for (int i = 0; i < 4; i++) {
      const int row = wave * 32 + i * 8;
      async_lds16(W + (long)(n0 + row + srow) * XSTR + k0 + scol8, Bs + row * 64);
    }
    __syncthreads();

#pragma unroll
    for (int ks = 0; ks < 64; ks += 32) {
      bf16x8 af[2], bfr[4];
#pragma unroll
      for (int mt = 0; mt < 2; mt++)
        af[mt] = *(const bf16x8*)(As + (wm + mt * 16 + ln) * 64 + ks + quad * 8);
#pragma unroll
      for (int nt = 0; nt < 4; nt++)
        bfr[nt] = *(const bf16x8*)(Bs + (wn + nt * 16 + ln) * 64 + ks + quad * 8);
#pragma unroll
      for (int mt = 0; mt < 2; mt++)
#pragma unroll
        for (int nt = 0; nt < 4; nt++)
          acc[mt][nt] = __builtin_amdgcn_mfma_f32_16x16x32_bf16(af[mt], bfr[nt], acc[mt][nt], 0, 0, 0);
    }
  }

#pragma unroll
  for (int nt = 0; nt < 4; nt++) {
    const int n = n0 + wn + nt * 16 + ln;
    const float bv = bias[n];
#pragma unroll
    for (int mt = 0; mt < 2; mt++) {
      const int r = r0 + wm + mt * 16 + quad * 4;
#pragma unroll
      for (int reg = 0; reg < 4; reg++)
        Y[(long)(r + reg) * GN + n] = acc[mt][nt][reg] + bv;
    }
  }
}

// ---------------------------------------------------------------------------
// Balanced shared-KV LDS flash attention (causal), exp2-domain.
// Block g (0..31) = 4 waves; wave->strip: {2g, 2g+1, 126-2g, 127-2g}.
// Block iteration count = nkt(127-2g) in [17,32] for ALL blocks (balanced).
// Waves with short strips go inactive early (barrier-wait only).
// K tile [64kv][64d] and V^T tile [64d][64kv] staged once per block per kt
// via global_load_lds, double-buffered; swizzled source+read (rule #21).
// ---------------------------------------------------------------------------
#define PSTR 72

__global__ __launch_bounds__(256, 3) void attn_causal(
    const unsigned short* __restrict__ Q,   // bf16 [4096][XSTR], pre-scaled
    const unsigned short* __restrict__ K,   // bf16 [4096][XSTR]
    const unsigned short* __restrict__ Vt,  // bf16 [1024][VSTR]
    unsigned short* __restrict__ O) {       // bf16 [4096][XSTR]
  __shared__ __align__(16) unsigned short Ks[2][64 * 64];  // [kv][d], swz slots
  __shared__ __align__(16) unsigned short Vs[2][64 * 64];  // [d][kv], swz slots
  __shared__ __align__(16) unsigned short Pb[4][16 * PSTR];

  const int g = blockIdx.x;        // 0..31; g=0 is longest (32 iters)
  const int bh = blockIdx.y;       // 0..31
  const int b = bh >> 4;
  const int h = bh & 15;

  const int tid = threadIdx.x;
  const int wave = tid >> 6;       // 0..3
  const int lane = tid & 63;
  const int quad = lane >> 4;
  const int ln = lane & 15;

  // balanced strip assignment: {2g, 2g+1, 126-2g, 127-2g}
  const int s = (wave < 2) ? (2 * g + wave) : (126 - 2 * g + (wave & 1));
  const int q0 = s * 16;
  const int nkt_self = (s >> 2) + 1;            // this wave's tile count
  const int nkt_blk = ((127 - 2 * g) >> 2) + 1; // block tile count, 17..32

  const unsigned short* Qb = Q + (long)b * S_LEN * XSTR + h * D_HEAD;
  const unsigned short* Kb = K + (long)b * S_LEN * XSTR + h * D_HEAD;
  const unsigned short* Vb = Vt + (long)h * D_HEAD * VSTR + b * S_LEN;

  // staging source (per thread): row = tid>>3 (0..31, +32 for 2nd chunk),
  // source slot pre-swizzled so linear LDS holds swizzled layout.
  const int srow = tid >> 3;
  const int sslot = (tid & 7) ^ (srow & 7);   // (row+32)&7 == row&7
  const unsigned short* Ksrc = Kb + (long)srow * XSTR + sslot * 8;
  const unsigned short* Vsrc = Vb + (long)srow * VSTR + sslot * 8;
  unsigned short* myP = Pb[wave];
  const int swz = ln & 7;  // row&7 for rows ct*16+ln (16 ≡ 0 mod 8)

  auto stage = [&](int buf, int kt) {
    const long kOff = (long)(kt * 64) * XSTR;
    const int vOff = kt * 64;
    async_lds16(Ksrc + kOff, &Ks[buf][wave * 512]);
    async_lds16(Ksrc + kOff + (long)32 * XSTR, &Ks[buf][2048 + wave * 512]);
    async_lds16(Vsrc + vOff, &Vs[buf][wave * 512]);
    async_lds16(Vsrc + (long)32 * VSTR + vOff, &Vs[buf][2048 + wave * 512]);
  };

  // Q fragments (held in registers for the whole kernel)
  bf16x8 qf0 = *(const bf16x8*)(Qb + (long)(q0 + ln) * XSTR + quad * 8);
  bf16x8 qf1 = *(const bf16x8*)(Qb + (long)(q0 + ln) * XSTR + 32 + quad * 8);

  float m = -1e30f, l = 0.f;
  floatx4 o[4];
#pragma unroll
  for (int nt = 0; nt < 4; nt++) o[nt] = (floatx4){0.f, 0.f, 0.f, 0.f};

  auto iterate = [&](int buf, int kt) {
    const int kv0 = kt * 64;
    const unsigned short* Kt = Ks[buf];
    const unsigned short* Vtile = Vs[buf];

    // ---- QK^T from LDS (swizzled read) ----
    floatx4 sS[4];
#pragma unroll
    for (int ct = 0; ct < 4; ct++) {
      const int row = ct * 16 + ln;
      bf16x8 k0 = *(const bf16x8*)(Kt + row * 64 + ((quad ^ swz) * 8));
      bf16x8 k1 = *(const bf16x8*)(Kt + row * 64 + (((4 + quad) ^ swz) * 8));
      sS[ct] = (floatx4){0.f, 0.f, 0.f, 0.f};
      sS[ct] = __builtin_amdgcn_mfma_f32_16x16x32_bf16(k0, qf0, sS[ct], 0, 0, 0);
      sS[ct] = __builtin_amdgcn_mfma_f32_16x16x32_bf16(k1, qf1, sS[ct], 0, 0, 0);
    }

    // ---- online softmax (exp2 domain; Q pre-scaled) ----
    float tmax = -1e30f;
    if (kt == nkt_self - 1) {  // diagonal tile: causal mask
      const int qg = q0 + ln;
#pragma unroll
      for (int ct = 0; ct < 4; ct++) {
        const int kvb = kv0 + ct * 16 + quad * 4;
#pragma unroll
        for (int reg = 0; reg < 4; reg++) {
          float sv = sS[ct][reg];
          if (kvb + reg > qg) sv = -1e30f;
          sS[ct][reg] = sv;
          tmax = fmaxf(tmax, sv);
        }
      }
    } else {
#pragma unroll
      for (int ct = 0; ct < 4; ct++)
#pragma unroll
        for (int reg = 0; reg < 4; reg++) tmax = fmaxf(tmax, sS[ct][reg]);
    }
    tmax = fmaxf(tmax, __shfl_xor(tmax, 16, 64));
    tmax = fmaxf(tmax, __shfl_xor(tmax, 32, 64));
    const float mnew = fmaxf(m, tmax);
    const float alpha = exp2f(m - mnew);
    m = mnew;
    float rsum = 0.f;
#pragma unroll
    for (int ct = 0; ct < 4; ct++) {
      u16x4 pk;
#pragma unroll
      for (int reg = 0; reg < 4; reg++) {
        const float p = exp2f(sS[ct][reg] - m);
        rsum += p;
        pk[reg] = f32_to_bf16(p);
      }
      *(u16x4*)(myP + ln * PSTR + ct * 16 + quad * 4) = pk;
    }
    rsum += __shfl_xor(rsum, 16, 64);
    rsum += __shfl_xor(rsum, 32, 64);
    l = l * alpha + rsum;
#pragma unroll
    for (int nt = 0; nt < 4; nt++)
#pragma unroll
      for (int reg = 0; reg < 4; reg++) o[nt][reg] *= alpha;

    __builtin_amdgcn_wave_barrier();

    // ---- PV: P via per-wave LDS transpose, V from shared LDS tile ----
    bf16x8 p0 = *(const bf16x8*)(myP + ln * PSTR + quad * 8);
    bf16x8 p1 = *(const bf16x8*)(myP + ln * PSTR + 32 + quad * 8);
#pragma unroll
    for (int nt = 0; nt < 4; nt++) {
      const int row = nt * 16 + ln;
      bf16x8 v0 = *(const bf16x8*)(Vtile + row * 64 + ((quad ^ swz) * 8));
      bf16x8 v1 = *(const bf16x8*)(Vtile + row * 64 + (((4 + quad) ^ swz) * 8));
      o[nt] = __builtin_amdgcn_mfma_f32_16x16x32_bf16(v0, p0, o[nt], 0, 0, 0);
      o[nt] = __builtin_amdgcn_mfma_f32_16x16x32_bf16(v1, p1, o[nt], 0, 0, 0);
    }
    __builtin_amdgcn_wave_barrier();
  };

  // ---- main loop: stage(kt+1) || compute(kt), one barrier per kt ----
  stage(0, 0);
  __syncthreads();  // drains vmcnt(0): tile 0 ready
#pragma unroll 1
  for (int kt = 0; kt < nkt_blk; kt++) {
    if (kt + 1 < nkt_blk) stage((kt + 1) & 1, kt + 1);
    if (kt < nkt_self) iterate(kt & 1, kt);
    __syncthreads();  // drains async loads for kt+1; guards buffer reuse
  }

  // ---- epilogue ----
  const float inv = 1.0f / l;
  unsigned short* op = O + (long)b * S_LEN * XSTR + (long)(q0 + ln) * XSTR + h * D_HEAD;
#pragma unroll
  for (int nt = 0; nt < 4; nt++) {
    u16x4 pk;
#pragma unroll
    for (int reg = 0; reg < 4; reg++) pk[reg] = f32_to_bf16(o[nt][reg] * inv);
    *(u16x4*)(op + nt * 16 + quad * 4) = pk;
  }
}

// ---------------------------------------------------------------------------
extern "C" void kernel_launch(void* const* d_in, const int* in_sizes, int n_in,
                              void* d_out, int out_size, void* d_ws, size_t ws_size,
                              hipStream_t stream) {
  const float* q = (const float*)d_in[0];
  const float* k = (const float*)d_in[1];
  const float* v = (const float*)d_in[2];
  // d_in[3] = causal mask (hardcoded)
  const float* w_q = (const float*)d_in[4];
  const float* b_q = (const float*)d_in[5];
  const float* w_k = (const float*)d_in[6];
  const float* b_k = (const float*)d_in[7];
  const float* w_v = (const float*)d_in[8];
  const float* b_v = (const float*)d_in[9];
  const float* w_o = (const float*)d_in[10];
  const float* b_o = (const float*)d_in[11];
  float* out = (float*)d_out;

  unsigned short* ws = (unsigned short*)d_ws;
  const long NR = (long)M_ROWS * XSTR;        // padded [4096][1088]
  const long NV = (long)1024 * VSTR;          // padded Vt
  const long NWALL = (long)4 * 1024 * XSTR;   // 4 weight mats
  const long NXALL = 3 * NR;                  // 3 inputs
  const long TOT_XPRE = 2 * NR + NV + NWALL + NXALL;
  const bool xpre = (ws_size >= (size_t)TOT_XPRE * sizeof(unsigned short));

  unsigned short *Qp, *Kp, *Vpt, *AO, *Wb, *Xb;
  if (xpre) {
    Qp = ws;                      // [0, NR)
    Kp = ws + NR;                 // [NR, 2NR)
    Vpt = ws + 2 * NR;            // [2NR, 2NR+NV)
    Wb = ws + 2 * NR + NV;        // 4 x [1024][XSTR]
    Xb = Wb + NWALL;              // 3 x [4096][XSTR]
    AO = Xb;                      // aliases Xb (dead after qkv_gemm)
  } else {
    Qp = ws;
    Kp = ws + NR;
    Vpt = ws + 2 * NR;
    AO = ws + 2 * NR + NV;
    Wb = AO + NR;
    Xb = nullptr;
  }

  cvt_w<<<dim3(1024, 4), 256, 0, stream>>>(w_q, w_k, w_v, w_o, Wb);
  if (xpre) {
    cvt_x<<<dim3(4096, 3), 256, 0, stream>>>(q, k, v, Xb);
    qkv_gemm<true><<<dim3(M_ROWS / 128, GN / 128, 3), 256, 0, stream>>>(
        q, k, v, Xb, Wb, b_q, b_k, b_v, Qp, Kp, Vpt);
  } else {
    qkv_gemm<false><<<dim3(M_ROWS / 128, GN / 128, 3), 256, 0, stream>>>(
        q, k, v, nullptr, Wb, b_q, b_k, b_v, Qp, Kp, Vpt);
  }
  attn_causal<<<dim3(32, 32), 256, 0, stream>>>(Qp, Kp, Vpt, AO);
  out_gemm<<<dim3(M_ROWS / 64, GN / 128), 256, 0, stream>>>(AO, Wb + 3 * (long)1024 * XSTR, b_o, out);
}

// Round 8
// 250.954 us; speedup vs baseline: 1.6684x; 1.0947x over previous
//
#include <hip/hip_runtime.h>

// ---------------------------------------------------------------------------
// MultiHeadAttentionBlock: B=2, S=2048, D=1024, H=16, DK=64, causal.
// FP32 I/O; bf16 MFMA compute, fp32 accumulate.
// r14: capacity >= work.  r13 diagnosis: 1024 blocks = 4 blocks/CU of work
//      but LDS 41984B caps 3/CU, and x-major dispatch gives each CU 4
//      same-duration blocks -> 3 run, 4th runs alone (serial tail).
//      Fix: single-buffer K/V LDS (25600B -> 6 blocks/CU): all blocks
//      resident from t=0, staging latency hidden by cross-block TLP
//      (m97-style 2-barrier loop).  Plus defer-max (T13): skip alpha/
//      o-rescale when __all(tmax <= m).  Rest identical to r13.
// ---------------------------------------------------------------------------

typedef __attribute__((ext_vector_type(8))) short bf16x8;     // 8 bf16 = 4 VGPRs
typedef __attribute__((ext_vector_type(4))) float floatx4;    // MFMA C/D
typedef __attribute__((ext_vector_type(4))) unsigned short u16x4;  // 8B packed bf16

#define S_LEN 2048
#define D_MODEL 1024
#define N_HEADS 16
#define D_HEAD 64
#define M_ROWS 4096   // B*S
#define QSCALE 0.18033688011112042f  // 0.125 * log2(e)

#define XSTR 1088   // padded row stride (elems) for [*,1024] bf16 buffers
#define VSTR 4160   // padded row stride (elems) for Vt [1024][4096]

__device__ __forceinline__ unsigned short f32_to_bf16(float f) {
  unsigned int u = __builtin_bit_cast(unsigned int, f);
  u += 0x7FFFu + ((u >> 16) & 1u);  // RNE
  return (unsigned short)(u >> 16);
}

// async 16B global->LDS copy: LDS dest is wave-uniform base + lane*16.
__device__ __forceinline__ void async_lds16(const unsigned short* g, unsigned short* l) {
  __builtin_amdgcn_global_load_lds(
      (const __attribute__((address_space(1))) unsigned int*)g,
      (__attribute__((address_space(3))) unsigned int*)l, 16, 0, 0);
}

// ---------------------------------------------------------------------------
// fp32 -> bf16 pre-passes (row-per-block, writing padded rows).
// ---------------------------------------------------------------------------
__global__ __launch_bounds__(256) void cvt_w(
    const float* __restrict__ w0, const float* __restrict__ w1,
    const float* __restrict__ w2, const float* __restrict__ w3,
    unsigned short* __restrict__ dst) {
  const int row = blockIdx.x;       // 0..1023
  const int z = blockIdx.y;         // 0..3
  const float* src = ((z == 0) ? w0 : (z == 1) ? w1 : (z == 2) ? w2 : w3) + (long)row * 1024;
  unsigned short* d = dst + (long)z * 1024 * XSTR + (long)row * XSTR;
  const int tid = threadIdx.x;
  float4 f = ((const float4*)src)[tid];
  u16x4 o;
  o[0] = f32_to_bf16(f.x); o[1] = f32_to_bf16(f.y);
  o[2] = f32_to_bf16(f.z); o[3] = f32_to_bf16(f.w);
  *(u16x4*)(d + tid * 4) = o;
}

__global__ __launch_bounds__(256) void cvt_x(
    const float* __restrict__ x0, const float* __restrict__ x1,
    const float* __restrict__ x2, unsigned short* __restrict__ dst) {
  const int row = blockIdx.x;       // 0..4095
  const int z = blockIdx.y;         // 0..2
  const float* src = ((z == 0) ? x0 : (z == 1) ? x1 : x2) + (long)row * 1024;
  unsigned short* d = dst + (long)z * M_ROWS * XSTR + (long)row * XSTR;
  const int tid = threadIdx.x;
  float4 f = ((const float4*)src)[tid];
  u16x4 o;
  o[0] = f32_to_bf16(f.x); o[1] = f32_to_bf16(f.y);
  o[2] = f32_to_bf16(f.z); o[3] = f32_to_bf16(f.w);
  *(u16x4*)(d + tid * 4) = o;
}

// ---------------------------------------------------------------------------
// Fused QKV projection. z = blockIdx.z.  Y = X @ W^T + b.
// 128x128 tile, BK=64, 4 waves x (64x64).  global_load_lds staging into
// linear [128][64] LDS, 2 barriers per K-step.  All bf16 operands padded.
// z=0: Y = (X Wq^T + bq) * QSCALE.  z=1: plain.  z=2: Y^T (V transposed).
// ---------------------------------------------------------------------------
#define GK 1024
#define GN 1024

template <bool XPRE>
__global__ __launch_bounds__(256, 3) void qkv_gemm(
    const float* __restrict__ Xq, const float* __restrict__ Xk, const float* __restrict__ Xv,
    const unsigned short* __restrict__ Xb,  // bf16, 3 x [4096][XSTR] (XPRE only)
    const unsigned short* __restrict__ Wb,  // bf16, 4 x [1024][XSTR]: [wq|wk|wv|wo]
    const float* __restrict__ bq, const float* __restrict__ bk, const float* __restrict__ bv,
    unsigned short* __restrict__ Yq, unsigned short* __restrict__ Yk,
    unsigned short* __restrict__ Yvt) {
  __shared__ __align__(16) unsigned short As[128 * 64];  // linear, stride 64
  __shared__ __align__(16) unsigned short Bs[128 * 64];

  const int z = blockIdx.z;
  const unsigned short* W = Wb + (long)z * 1024 * XSTR;
  const float* bias = (z == 0) ? bq : ((z == 1) ? bk : bv);

  const int r0 = blockIdx.x * 128;
  const int n0 = blockIdx.y * 128;
  const int tid = threadIdx.x;
  const int lane = tid & 63;
  const int wave = tid >> 6;
  const int quad = lane >> 4;
  const int ln = lane & 15;
  const int wm = (wave >> 1) * 64;
  const int wn = (wave & 1) * 64;

  floatx4 acc[4][4];
#pragma unroll
  for (int i = 0; i < 4; i++)
#pragma unroll
    for (int j = 0; j < 4; j++) acc[i][j] = (floatx4){0.f, 0.f, 0.f, 0.f};

  // async staging geometry: per wave, 4 chunks of 1 KiB each per tile.
  const int srow = (lane >> 3);        // 0..7
  const int scol8 = (lane & 7) * 8;    // elem offset of this lane's 16B chunk
  const unsigned short* ApH = nullptr;
  const float* ApF = nullptr;
  if constexpr (XPRE) {
    ApH = Xb + (long)z * M_ROWS * XSTR;
  } else {
    ApF = (z == 0) ? Xq : ((z == 1) ? Xk : Xv);
  }

  for (int k0 = 0; k0 < GK; k0 += 64) {
    __syncthreads();  // all waves done reading previous tile
    if constexpr (XPRE) {
#pragma unroll
      for (int i = 0; i < 4; i++) {
        const int row = wave * 32 + i * 8;
        async_lds16(ApH + (long)(r0 + row + srow) * XSTR + k0 + scol8,
                    As + row * 64);
        async_lds16(W + (long)(n0 + row + srow) * XSTR + k0 + scol8,
                    Bs + row * 64);
      }
    } else {
      // A: register-stage fp32 -> bf16 (32 elems/thread), B: async
      const int arow = tid >> 1;
      const int acol = (tid & 1) * 32;
      unsigned short ua[32] __attribute__((aligned(16)));
      float fa[32] __attribute__((aligned(16)));
#pragma unroll
      for (int c = 0; c < 8; c++)
        *(float4*)(fa + c * 4) = *(const float4*)(ApF + (long)(r0 + arow) * GK + k0 + acol + c * 4);
#pragma unroll
      for (int j = 0; j < 32; j++) ua[j] = f32_to_bf16(fa[j]);
      *(float4*)(As + arow * 64 + acol) = *(float4*)(ua);
      *(float4*)(As + arow * 64 + acol + 8) = *(float4*)(ua + 8);
      *(float4*)(As + arow * 64 + acol + 16) = *(float4*)(ua + 16);
      *(float4*)(As + arow * 64 + acol + 24) = *(float4*)(ua + 24);
#pragma unroll
      for (int i = 0; i < 4; i++) {
        const int row = wave * 32 + i * 8;
        async_lds16(W + (long)(n0 + row + srow) * XSTR + k0 + scol8,
                    Bs + row * 64);
      }
    }
    __syncthreads();  // vmcnt(0)+lgkmcnt(0) drain happens here

#pragma unroll
    for (int ks = 0; ks < 64; ks += 32) {
      bf16x8 af[4], bfr[4];
#pragma unroll
      for (int mt = 0; mt < 4; mt++)
        af[mt] = *(const bf16x8*)(As + (wm + mt * 16 + ln) * 64 + ks + quad * 8);
#pragma unroll
      for (int nt = 0; nt < 4; nt++)
        bfr[nt] = *(const bf16x8*)(Bs + (wn + nt * 16 + ln) * 64 + ks + quad * 8);
#pragma unroll
      for (int mt = 0; mt < 4; mt++)
#pragma unroll
        for (int nt = 0; nt < 4; nt++)
          acc[mt][nt] = __builtin_amdgcn_mfma_f32_16x16x32_bf16(af[mt], bfr[nt], acc[mt][nt], 0, 0, 0);
    }
  }

#pragma unroll
  for (int nt = 0; nt < 4; nt++) {
    const int n = n0 + wn + nt * 16 + ln;
    const float bv = bias[n];
#pragma unroll
    for (int mt = 0; mt < 4; mt++) {
      const int r = r0 + wm + mt * 16 + quad * 4;
      if (z == 2) {  // V^T: Yvt[n][r..r+3]
        u16x4 pk;
#pragma unroll
        for (int reg = 0; reg < 4; reg++) pk[reg] = f32_to_bf16(acc[mt][nt][reg] + bv);
        *(u16x4*)(Yvt + (long)n * VSTR + r) = pk;
      } else if (z == 0) {  // Q pre-scaled for exp2-domain softmax
#pragma unroll
        for (int reg = 0; reg < 4; reg++)
          Yq[(long)(r + reg) * XSTR + n] = f32_to_bf16((acc[mt][nt][reg] + bv) * QSCALE);
      } else {
#pragma unroll
        for (int reg = 0; reg < 4; reg++)
          Yk[(long)(r + reg) * XSTR + n] = f32_to_bf16(acc[mt][nt][reg] + bv);
      }
    }
  }
}

// ---------------------------------------------------------------------------
// Out projection: Y fp32 = AO(bf16,[4096][XSTR]) @ Wo(bf16,[1024][XSTR])^T + b.
// 64x128 tile, BK=64, async staging into linear LDS.
// ---------------------------------------------------------------------------
__global__ __launch_bounds__(256, 3) void out_gemm(
    const unsigned short* __restrict__ X,
    const unsigned short* __restrict__ W,
    const float* __restrict__ bias,
    float* __restrict__ Y) {
  __shared__ __align__(16) unsigned short As[64 * 64];    // linear, stride 64
  __shared__ __align__(16) unsigned short Bs[128 * 64];

  const int r0 = blockIdx.x * 64;
  const int n0 = blockIdx.y * 128;
  const int tid = threadIdx.x;
  const int lane = tid & 63;
  const int wave = tid >> 6;
  const int quad = lane >> 4;
  const int ln = lane & 15;
  const int wm = (wave >> 1) * 32;
  const int wn = (wave & 1) * 64;

  floatx4 acc[2][4];
#pragma unroll
  for (int i = 0; i < 2; i++)
#pragma unroll
    for (int j = 0; j < 4; j++) acc[i][j] = (floatx4){0.f, 0.f, 0.f, 0.f};

  const int srow = (lane >> 3);
  const int scol8 = (lane & 7) * 8;

  for (int k0 = 0; k0 < GK; k0 += 64) {
    __syncthreads();
    // A tile 64x64 = 8 KiB = 2 chunks/wave; B tile 128x64 = 4 chunks/wave
#pragma unroll
    for (int i = 0; i < 2; i++) {
      const int row = wave * 16 + i * 8;
      async_lds16(X + (long)(r0 + row + srow) * XSTR + k0 + scol8, As + row * 64);
    }
#pragma unroll
    for (int i = 0; i < 4; i++) {
      const int row = wave * 32 + i * 8;
      async_lds16(W + (long)(n0 + row + srow) * XSTR + k0 + scol8, Bs + row * 64);
    }
    __syncthreads();

#pragma unroll
    for (int ks = 0; ks < 64; ks += 32) {
      bf16x8 af[2], bfr[4];
#pragma unroll
      for (int mt = 0; mt < 2; mt++)
        af[mt] = *(const bf16x8*)(As + (wm + mt * 16 + ln) * 64 + ks + quad * 8);
#pragma unroll
      for (int nt = 0; nt < 4; nt++)
        bfr[nt] = *(const bf16x8*)(Bs + (wn + nt * 16 + ln) * 64 + ks + quad * 8);
#pragma unroll
      for (int mt = 0; mt < 2; mt++)
#pragma unroll
        for (int nt = 0; nt < 4; nt++)
          acc[mt][nt] = __builtin_amdgcn_mfma_f32_16x16x32_bf16(af[mt], bfr[nt], acc[mt][nt], 0, 0, 0);
    }
  }

#pragma unroll
  for (int nt = 0; nt < 4; nt++) {
    const int n = n0 + wn + nt * 16 + ln;
    const float bv = bias[n];
#pragma unroll
    for (int mt = 0; mt < 2; mt++) {
      const int r = r0 + wm + mt * 16 + quad * 4;
#pragma unroll
      for (int reg = 0; reg < 4; reg++)
        Y[(long)(r + reg) * GN + n] = acc[mt][nt][reg] + bv;
    }
  }
}

// ---------------------------------------------------------------------------
// Balanced shared-KV LDS flash attention (causal), exp2-domain.
// Block g (0..31) = 4 waves; wave->strip: {2g, 2g+1, 126-2g, 127-2g}.
// Block iteration count = nkt(127-2g) in [17,32] for ALL blocks (balanced).
// Single-buffered K/V LDS (25600 B -> 6 blocks/CU: all 4 blocks/CU of work
// resident from t=0); staging latency hidden by cross-block TLP.
// Defer-max (T13): skip alpha/o-rescale when no lane raised its row max.
// ---------------------------------------------------------------------------
#define PSTR 72

__global__ __launch_bounds__(256, 4) void attn_causal(
    const unsigned short* __restrict__ Q,   // bf16 [4096][XSTR], pre-scaled
    const unsigned short* __restrict__ K,   // bf16 [4096][XSTR]
    const unsigned short* __restrict__ Vt,  // bf16 [1024][VSTR]
    unsigned short* __restrict__ O) {       // bf16 [4096][XSTR]
  __shared__ __align__(16) unsigned short Ks[64 * 64];  // [kv][d], swz slots
  __shared__ __align__(16) unsigned short Vs[64 * 64];  // [d][kv], swz slots
  __shared__ __align__(16) unsigned short Pb[4][16 * PSTR];

  const int g = blockIdx.x;        // 0..31; g=0 is longest (32 iters)
  const int bh = blockIdx.y;       // 0..31
  const int b = bh >> 4;
  const int h = bh & 15;

  const int tid = threadIdx.x;
  const int wave = tid >> 6;       // 0..3
  const int lane = tid & 63;
  const int quad = lane >> 4;
  const int ln = lane & 15;

  // balanced strip assignment: {2g, 2g+1, 126-2g, 127-2g}
  const int s = (wave < 2) ? (2 * g + wave) : (126 - 2 * g + (wave & 1));
  const int q0 = s * 16;
  const int nkt_self = (s >> 2) + 1;            // this wave's tile count
  const int nkt_blk = ((127 - 2 * g) >> 2) + 1; // block tile count, 17..32

  const unsigned short* Qb = Q + (long)b * S_LEN * XSTR + h * D_HEAD;
  const unsigned short* Kb = K + (long)b * S_LEN * XSTR + h * D_HEAD;
  const unsigned short* Vb = Vt + (long)h * D_HEAD * VSTR + b * S_LEN;

  // staging source (per thread): row = tid>>3 (0..31, +32 for 2nd chunk),
  // source slot pre-swizzled so linear LDS holds swizzled layout.
  const int srow = tid >> 3;
  const int sslot = (tid & 7) ^ (srow & 7);   // (row+32)&7 == row&7
  const unsigned short* Ksrc = Kb + (long)srow * XSTR + sslot * 8;
  const unsigned short* Vsrc = Vb + (long)srow * VSTR + sslot * 8;
  unsigned short* myP = Pb[wave];
  const int swz = ln & 7;  // row&7 for rows ct*16+ln (16 ≡ 0 mod 8)

  auto stage = [&](int kt) {
    const long kOff = (long)(kt * 64) * XSTR;
    const int vOff = kt * 64;
    async_lds16(Ksrc + kOff, &Ks[wave * 512]);
    async_lds16(Ksrc + kOff + (long)32 * XSTR, &Ks[2048 + wave * 512]);
    async_lds16(Vsrc + vOff, &Vs[wave * 512]);
    async_lds16(Vsrc + (long)32 * VSTR + vOff, &Vs[2048 + wave * 512]);
  };

  // Q fragments (held in registers for the whole kernel)
  bf16x8 qf0 = *(const bf16x8*)(Qb + (long)(q0 + ln) * XSTR + quad * 8);
  bf16x8 qf1 = *(const bf16x8*)(Qb + (long)(q0 + ln) * XSTR + 32 + quad * 8);

  float m = -1e30f, l = 0.f;
  floatx4 o[4];
#pragma unroll
  for (int nt = 0; nt < 4; nt++) o[nt] = (floatx4){0.f, 0.f, 0.f, 0.f};

  auto iterate = [&](int kt) {
    const int kv0 = kt * 64;

    // ---- QK^T from LDS (swizzled read) ----
    floatx4 sS[4];
#pragma unroll
    for (int ct = 0; ct < 4; ct++) {
      const int row = ct * 16 + ln;
      bf16x8 k0 = *(const bf16x8*)(Ks + row * 64 + ((quad ^ swz) * 8));
      bf16x8 k1 = *(const bf16x8*)(Ks + row * 64 + (((4 + quad) ^ swz) * 8));
      sS[ct] = (floatx4){0.f, 0.f, 0.f, 0.f};
      sS[ct] = __builtin_amdgcn_mfma_f32_16x16x32_bf16(k0, qf0, sS[ct], 0, 0, 0);
      sS[ct] = __builtin_amdgcn_mfma_f32_16x16x32_bf16(k1, qf1, sS[ct], 0, 0, 0);
    }

    // ---- online softmax (exp2 domain; Q pre-scaled) ----
    float tmax = -1e30f;
    if (kt == nkt_self - 1) {  // diagonal tile: causal mask
      const int qg = q0 + ln;
#pragma unroll
      for (int ct = 0; ct < 4; ct++) {
        const int kvb = kv0 + ct * 16 + quad * 4;
#pragma unroll
        for (int reg = 0; reg < 4; reg++) {
          float sv = sS[ct][reg];
          if (kvb + reg > qg) sv = -1e30f;
          sS[ct][reg] = sv;
          tmax = fmaxf(tmax, sv);
        }
      }
    } else {
#pragma unroll
      for (int ct = 0; ct < 4; ct++)
#pragma unroll
        for (int reg = 0; reg < 4; reg++) tmax = fmaxf(tmax, sS[ct][reg]);
    }
    tmax = fmaxf(tmax, __shfl_xor(tmax, 16, 64));
    tmax = fmaxf(tmax, __shfl_xor(tmax, 32, 64));
    // defer-max (T13): only rescale when some row max actually grew
    if (!__all(tmax <= m)) {
      const float mnew = fmaxf(m, tmax);
      const float alpha = exp2f(m - mnew);
      m = mnew;
      l *= alpha;
#pragma unroll
      for (int nt = 0; nt < 4; nt++)
#pragma unroll
        for (int reg = 0; reg < 4; reg++) o[nt][reg] *= alpha;
    }
    float rsum = 0.f;
#pragma unroll
    for (int ct = 0; ct < 4; ct++) {
      u16x4 pk;
#pragma unroll
      for (int reg = 0; reg < 4; reg++) {
        const float p = exp2f(sS[ct][reg] - m);
        rsum += p;
        pk[reg] = f32_to_bf16(p);
      }
      *(u16x4*)(myP + ln * PSTR + ct * 16 + quad * 4) = pk;
    }
    rsum += __shfl_xor(rsum, 16, 64);
    rsum += __shfl_xor(rsum, 32, 64);
    l += rsum;

    __builtin_amdgcn_wave_barrier();

    // ---- PV: P via per-wave LDS transpose, V from shared LDS tile ----
    bf16x8 p0 = *(const bf16x8*)(myP + ln * PSTR + quad * 8);
    bf16x8 p1 = *(const bf16x8*)(myP + ln * PSTR + 32 + quad * 8);
#pragma unroll
    for (int nt = 0; nt < 4; nt++) {
      const int row = nt * 16 + ln;
      bf16x8 v0 = *(const bf16x8*)(Vs + row * 64 + ((quad ^ swz) * 8));
      bf16x8 v1 = *(const bf16x8*)(Vs + row * 64 + (((4 + quad) ^ swz) * 8));
      o[nt] = __builtin_amdgcn_mfma_f32_16x16x32_bf16(v0, p0, o[nt], 0, 0, 0);
      o[nt] = __builtin_amdgcn_mfma_f32_16x16x32_bf16(v1, p1, o[nt], 0, 0, 0);
    }
  };

  // ---- main loop: stage(kt); drain; compute(kt); guard ----
#pragma unroll 1
  for (int kt = 0; kt < nkt_blk; kt++) {
    stage(kt);
    __syncthreads();  // drains vmcnt(0): tile ready
    if (kt < nkt_self) iterate(kt);
    __syncthreads();  // all waves done reading before next overwrite
  }

  // ---- epilogue ----
  const float inv = 1.0f / l;
  unsigned short* op = O + (long)b * S_LEN * XSTR + (long)(q0 + ln) * XSTR + h * D_HEAD;
#pragma unroll
  for (int nt = 0; nt < 4; nt++) {
    u16x4 pk;
#pragma unroll
    for (int reg = 0; reg < 4; reg++) pk[reg] = f32_to_bf16(o[nt][reg] * inv);
    *(u16x4*)(op + nt * 16 + quad * 4) = pk;
  }
}

// ---------------------------------------------------------------------------
extern "C" void kernel_launch(void* const* d_in, const int* in_sizes, int n_in,
                              void* d_out, int out_size, void* d_ws, size_t ws_size,
                              hipStream_t stream) {
  const float* q = (const float*)d_in[0];
  const float* k = (const float*)d_in[1];
  const float* v = (const float*)d_in[2];
  // d_in[3] = causal mask (hardcoded)
  const float* w_q = (const float*)d_in[4];
  const float* b_q = (const float*)d_in[5];
  const float* w_k = (const float*)d_in[6];
  const float* b_k = (const float*)d_in[7];
  const float* w_v = (const float*)d_in[8];
  const float* b_v = (const float*)d_in[9];
  const float* w_o = (const float*)d_in[10];
  const float* b_o = (const float*)d_in[11];
  float* out = (float*)d_out;

  unsigned short* ws = (unsigned short*)d_ws;
  const long NR = (long)M_ROWS * XSTR;        // padded [4096][1088]
  const long NV = (long)1024 * VSTR;          // padded Vt
  const long NWALL = (long)4 * 1024 * XSTR;   // 4 weight mats
  const long NXALL = 3 * NR;                  // 3 inputs
  const long TOT_XPRE = 2 * NR + NV + NWALL + NXALL;
  const bool xpre = (ws_size >= (size_t)TOT_XPRE * sizeof(unsigned short));

  unsigned short *Qp, *Kp, *Vpt, *AO, *Wb, *Xb;
  if (xpre) {
    Qp = ws;                      // [0, NR)
    Kp = ws + NR;                 // [NR, 2NR)
    Vpt = ws + 2 * NR;            // [2NR, 2NR+NV)
    Wb = ws + 2 * NR + NV;        // 4 x [1024][XSTR]
    Xb = Wb + NWALL;              // 3 x [4096][XSTR]
    AO = Xb;                      // aliases Xb (dead after qkv_gemm)
  } else {
    Qp = ws;
    Kp = ws + NR;
    Vpt = ws + 2 * NR;
    AO = ws + 2 * NR + NV;
    Wb = AO + NR;
    Xb = nullptr;
  }

  cvt_w<<<dim3(1024, 4), 256, 0, stream>>>(w_q, w_k, w_v, w_o, Wb);
  if (xpre) {
    cvt_x<<<dim3(4096, 3), 256, 0, stream>>>(q, k, v, Xb);
    qkv_gemm<true><<<dim3(M_ROWS / 128, GN / 128, 3), 256, 0, stream>>>(
        q, k, v, Xb, Wb, b_q, b_k, b_v, Qp, Kp, Vpt);
  } else {
    qkv_gemm<false><<<dim3(M_ROWS / 128, GN / 128, 3), 256, 0, stream>>>(
        q, k, v, nullptr, Wb, b_q, b_k, b_v, Qp, Kp, Vpt);
  }
  attn_causal<<<dim3(32, 32), 256, 0, stream>>>(Qp, Kp, Vpt, AO);
  out_gemm<<<dim3(M_ROWS / 64, GN / 128), 256, 0, stream>>>(AO, Wb + 3 * (long)1024 * XSTR, b_o, out);
}